// Round 10
// baseline (8200.850 us; speedup 1.0000x reference)
//
#include <hip/hip_runtime.h>
#include <hip/hip_bf16.h>
#include <cstdint>
#include <cstddef>

typedef _Float16 half_t;
typedef decltype(__builtin_amdgcn_cvt_pkrtz(0.f, 0.f)) h2;  // v2f16

__device__ __forceinline__ h2 pk2(float a, float b) { return __builtin_amdgcn_cvt_pkrtz(a, b); }
__device__ __forceinline__ float fdot2f(h2 a, h2 b, float c) { return __builtin_amdgcn_fdot2(a, b, c, false); }
__device__ __forceinline__ h2 u2h(uint32_t u) { union { uint32_t u; h2 h; } v; v.u = u; return v.h; }

#define WAVE_SYNC() asm volatile("s_waitcnt lgkmcnt(0)" ::: "memory")
// Block barrier WITHOUT vmcnt drain: global loads stay in flight.
#define BLOCK_SYNC()                                   \
  do {                                                 \
    asm volatile("s_waitcnt lgkmcnt(0)" ::: "memory"); \
    __builtin_amdgcn_s_barrier();                      \
    asm volatile("" ::: "memory");                     \
  } while (0)

template <int NQ>
__device__ __forceinline__ void fetch_q(const half_t* hb, uint4* q) {
  const uint4* p = (const uint4*)hb;
#pragma unroll
  for (int i = 0; i < NQ; ++i) q[i] = p[i];
}

// 8 f16-MACs per uint4, FOUR independent accumulator chains.
template <int NQ>
__device__ __forceinline__ void dot4(const h2* w, const uint4* q, float* a) {
#pragma unroll
  for (int i = 0; i < NQ; ++i) {
    a[0] = fdot2f(w[4 * i + 0], u2h(q[i].x), a[0]);
    a[1] = fdot2f(w[4 * i + 1], u2h(q[i].y), a[1]);
    a[2] = fdot2f(w[4 * i + 2], u2h(q[i].z), a[2]);
    a[3] = fdot2f(w[4 * i + 3], u2h(q[i].w), a[3]);
  }
}

__device__ __forceinline__ void load_row_h2(const float* src, int nf, h2* dst) {
  const float2* s2 = (const float2*)src;
  for (int p = 0; p < nf / 2; ++p) { float2 v = s2[p]; dst[p] = pk2(v.x, v.y); }
}

__device__ __forceinline__ void gconst(int gt, float& s, float& a, float& b) {
  const bool isT = (gt == 2);
  s = isT ? -2.88539008f : -1.44269504f;
  a = isT ? 2.f : 1.f;
  b = isT ? -1.f : 0.f;
}

__device__ __forceinline__ float act_sig(float x) {
  float e = exp2f(-1.44269504f * x);
  return __builtin_amdgcn_rcpf(1.f + e);
}
__device__ __forceinline__ float act_tanh(float x) {
  float e = exp2f(-2.88539008f * x);
  return fmaf(2.f, __builtin_amdgcn_rcpf(1.f + e), -1.f);
}
__device__ __forceinline__ float act_rt(float x, float s, float a, float b) {
  float e = exp2f(s * x);
  return fmaf(a, __builtin_amdgcn_rcpf(1.f + e), b);
}

__device__ __forceinline__ float comb4(float gi, float gf, float gg, float go, float& c) {
  c = fmaf(gf, c, gi * gg);
  float e2 = exp2f(-2.88539008f * c);
  return go * fmaf(2.f, __builtin_amdgcn_rcpf(1.f + e2), -1.f);
}

// Pair layers (pow2 H): lane l<32 holds gates (i,f), lane l+32 (g,o) of the
// same unit. One shfl_xor(32) pair completes the set.
__device__ __forceinline__ float pair_combine(float gv0, float gv1, int l, float& c) {
  float sw0 = __shfl_xor(gv0, 32, 64);
  float sw1 = __shfl_xor(gv1, 32, 64);
  const bool lo = (l < 32);
  float gi = lo ? gv0 : sw0, gf = lo ? gv1 : sw1;
  float gg = lo ? sw0 : gv0, go = lo ? sw1 : gv1;
  return comb4(gi, gf, gg, go, c);
}

// ===================== Fused autoencoder, 2 timesteps per barrier =====================
// 512 blocks x 256 threads, one block per chain. Roles rotated by blockIdx&1.
// Every recurrent layer is SINGLE-WAVE (intra-period h reuse is intra-wave only;
// all cross-wave hand-offs are previous-period = barrier-separated).
// Enc roles: 0=e1-rec(96d/step) 1=e2 pair(80) 2=e3(24) 3=x-producer+e1-xGEMM(96)
// Dec roles: 0=d1+xg_d2(80) 1=d2-rec(96, skew3) 2=d3-rec unit-per-lane(128, skew7)
//            3=d3-xg producer(96, xg for tau=s-5)
__global__ __launch_bounds__(256, 2) void ae_ker(
    const float* __restrict__ W0, const float* __restrict__ U0, const float* __restrict__ b0i, const float* __restrict__ b0h,
    const float* __restrict__ W1, const float* __restrict__ U1, const float* __restrict__ b1i, const float* __restrict__ b1h,
    const float* __restrict__ W2, const float* __restrict__ U2, const float* __restrict__ b2i, const float* __restrict__ b2h,
    const float* __restrict__ W3, const float* __restrict__ U3, const float* __restrict__ b3i, const float* __restrict__ b3h,
    const float* __restrict__ W4, const float* __restrict__ U4, const float* __restrict__ b4i, const float* __restrict__ b4h,
    const float* __restrict__ W5, const float* __restrict__ U5, const float* __restrict__ b5i, const float* __restrict__ b5h,
    const float* __restrict__ x, float* __restrict__ out, int T) {
  __shared__ __align__(16) half_t hb1e[4][48];
  __shared__ __align__(16) half_t hb2e[4][32];
  __shared__ __align__(16) half_t hb3e[4][16];
  __shared__ __align__(16) uint32_t xrow16[2][32];
  __shared__ __align__(16) float xg1[2][2][192];  // [bank][sub][row]
  __shared__ __align__(16) float latb[16];
  __shared__ __align__(16) half_t hb1d[4][32];
  __shared__ __align__(16) half_t hb2d[4][48];
  __shared__ __align__(16) half_t hb3r[2][64];    // d3-rec private ping-pong
  __shared__ __align__(16) float xg2[2][2][192];
  __shared__ __align__(16) float xg3[2][2][256];  // d3-xg -> d3-rec (bias folded)

  const int tid = threadIdx.x, wv = tid >> 6, l = tid & 63, b = blockIdx.x;
  const int role = (wv + ((b & 1) << 1)) & 3;
  const int uu = (l < 48) ? l : 47;

  if (tid < 48) {
#pragma unroll
    for (int s = 0; s < 4; ++s) hb1e[s][tid] = (half_t)0.f;
  }
  if (tid < 32) {
#pragma unroll
    for (int s = 0; s < 4; ++s) hb2e[s][tid] = (half_t)0.f;
  }
  if (tid < 16) {
#pragma unroll
    for (int s = 0; s < 4; ++s) hb3e[s][tid] = (half_t)0.f;
  }

  h2 w[128];
  float bias[3] = {0.f, 0.f, 0.f};
  float bx[4] = {0.f, 0.f, 0.f, 0.f};
  float sA[2], aA[2], bB[2];
  float c = 0.f;
  float2 va = {0.f, 0.f}, vb = {0.f, 0.f}, vc = {0.f, 0.f}, vd = {0.f, 0.f};
  const float2* xp = nullptr;

  // ---------------- encoder weight load ----------------
  if (role == 0) {  // e1-rec: unit-per-lane, Whh rows j*48+uu
#pragma unroll
    for (int j = 0; j < 4; ++j)
      load_row_h2(U0 + (size_t)(j * 48 + uu) * 48, 48, w + j * 24);
  } else if (role == 1) {  // e2 pair
    const int u = l & 31, g0 = (l < 32) ? 0 : 2;
#pragma unroll
    for (int j = 0; j < 2; ++j) {
      const int r = (g0 + j) * 32 + u;
      load_row_h2(W1 + (size_t)r * 48, 48, w + j * 40);
      load_row_h2(U1 + (size_t)r * 32, 32, w + j * 40 + 24);
      bias[j] = b1i[r] + b1h[r];
      gconst(g0 + j, sA[j], aA[j], bB[j]);
    }
  } else if (role == 2) {  // e3: row r=l
    load_row_h2(W2 + (size_t)l * 32, 32, w);
    load_row_h2(U2 + (size_t)l * 16, 16, w + 16);
    bias[0] = b2i[l] + b2h[l];
    gconst(l >> 4, sA[0], aA[0], bB[0]);
  } else {  // producer: Wih_e1 rows 64j+l
#pragma unroll
    for (int j = 0; j < 3; ++j) {
      const int r = 64 * j + l;
      load_row_h2(W0 + (size_t)r * 64, 64, w + j * 32);
      bias[j] = b0i[r] + b0h[r];
    }
    xp = (const float2*)(x + (size_t)b * T * 64) + (l & 31);
    if (l < 32) {
      va = xp[0]; vb = xp[32];
      vc = xp[64]; vd = xp[96];
      union { h2 h; uint32_t u; } c0, c1;
      c0.h = pk2(va.x, va.y);
      c1.h = pk2(vb.x, vb.y);
      xrow16[0][l] = c0.u;
      xrow16[1][l] = c1.u;
      va = vc; vb = vd;
      vc = xp[128]; vd = xp[160];
    }
    WAVE_SYNC();
    uint4 xq0[8], xq1[8];
    fetch_q<8>((const half_t*)&xrow16[0][0], xq0);
    fetch_q<8>((const half_t*)&xrow16[1][0], xq1);
#pragma unroll
    for (int j = 0; j < 3; ++j) {
      float a[4] = {bias[j], 0.f, 0.f, 0.f};
      dot4<8>(w + j * 32, xq0, a);
      xg1[0][0][64 * j + l] = (a[0] + a[1]) + (a[2] + a[3]);
    }
#pragma unroll
    for (int j = 0; j < 3; ++j) {
      float a[4] = {bias[j], 0.f, 0.f, 0.f};
      dot4<8>(w + j * 32, xq1, a);
      xg1[0][1][64 * j + l] = (a[0] + a[1]) + (a[2] + a[3]);
    }
  }
  BLOCK_SYNC();

  // ---------------- encoder: one barrier per 2 steps ----------------
  auto esub = [&](const bool G, int p, int pp, int sub, uint4* xq0, uint4* xq1) {
    if (role == 0) {
      const int t_ = 2 * p + sub;
      if (!G || t_ < T) {
        float xgv[4];
#pragma unroll
        for (int j = 0; j < 4; ++j) xgv[j] = xg1[pp][sub][j * 48 + uu];
        uint4 hq[6];
        fetch_q<6>(&hb1e[(2 * pp + sub + 3) & 3][0], hq);
        __builtin_amdgcn_s_setprio(1);
        float gv[4];
#pragma unroll
        for (int j = 0; j < 4; ++j) {
          float a[4] = {xgv[j], 0.f, 0.f, 0.f};
          dot4<6>(w + j * 24, hq, a);
          float pre = (a[0] + a[1]) + (a[2] + a[3]);
          gv[j] = (j == 2) ? act_tanh(pre) : act_sig(pre);
        }
        __builtin_amdgcn_s_setprio(0);
        float h = comb4(gv[0], gv[1], gv[2], gv[3], c);
        if (l < 48) hb1e[(2 * pp + sub) & 3][l] = (half_t)h;
      }
    } else if (role == 1) {
      const int t_ = 2 * p + sub - 2;
      if (!G || (unsigned)t_ < (unsigned)T) {
        uint4 xv[6], hq[4];
        fetch_q<6>(&hb1e[(2 * pp + sub + 2) & 3][0], xv);
        fetch_q<4>(&hb2e[(2 * pp + sub + 1) & 3][0], hq);
        float gv[2];
#pragma unroll
        for (int j = 0; j < 2; ++j) {
          float a[4] = {bias[j], 0.f, 0.f, 0.f};
          dot4<6>(w + j * 40, xv, a);
          dot4<4>(w + j * 40 + 24, hq, a);
          gv[j] = act_rt((a[0] + a[1]) + (a[2] + a[3]), sA[j], aA[j], bB[j]);
        }
        float h = pair_combine(gv[0], gv[1], l, c);
        if (l < 32) hb2e[(2 * pp + sub + 2) & 3][l & 31] = (half_t)h;
      }
    } else if (role == 2) {
      const int t_ = 2 * p + sub - 4;
      if (!G || (unsigned)t_ < (unsigned)T) {
        uint4 xv[4], hq[2];
        fetch_q<4>(&hb2e[(2 * pp + sub) & 3][0], xv);
        fetch_q<2>(&hb3e[(2 * pp + sub + 3) & 3][0], hq);
        float a[4] = {bias[0], 0.f, 0.f, 0.f};
        dot4<4>(w, xv, a);
        dot4<2>(w + 16, hq, a);
        float gvv = act_rt((a[0] + a[1]) + (a[2] + a[3]), sA[0], aA[0], bB[0]);
        float s1 = __shfl_xor(gvv, 16, 64);
        float r0 = __shfl_xor(gvv, 32, 64);
        float r1 = __shfl_xor(s1, 32, 64);
        float h = comb4(gvv, s1, r0, r1, c);
        if (l < 16) {
          hb3e[(2 * pp + sub) & 3][l] = (half_t)h;
          if (G && t_ == T - 1) latb[l] = h;
        }
      }
    } else {
      if (sub == 0) {
        if (!G || 2 * p + 3 < T) {
          if (l < 32) {
            union { h2 h; uint32_t u; } c0, c1;
            c0.h = pk2(va.x, va.y);
            c1.h = pk2(vb.x, vb.y);
            xrow16[0][l] = c0.u;
            xrow16[1][l] = c1.u;
            va = vc; vb = vd;
            if (!G || 2 * p + 7 < T) {
              vc = xp[(size_t)(2 * p + 6) * 32];
              vd = xp[(size_t)(2 * p + 7) * 32];
            }
          }
          WAVE_SYNC();
          fetch_q<8>((const half_t*)&xrow16[0][0], xq0);
          fetch_q<8>((const half_t*)&xrow16[1][0], xq1);
          __builtin_amdgcn_s_setprio(1);
#pragma unroll
          for (int j = 0; j < 3; ++j) {
            float a[4] = {bias[j], 0.f, 0.f, 0.f};
            dot4<8>(w + j * 32, xq0, a);
            xg1[pp ^ 1][0][64 * j + l] = (a[0] + a[1]) + (a[2] + a[3]);
          }
          __builtin_amdgcn_s_setprio(0);
        }
      } else {
        if (!G || 2 * p + 3 < T) {
          __builtin_amdgcn_s_setprio(1);
#pragma unroll
          for (int j = 0; j < 3; ++j) {
            float a[4] = {bias[j], 0.f, 0.f, 0.f};
            dot4<8>(w + j * 32, xq1, a);
            xg1[pp ^ 1][1][64 * j + l] = (a[0] + a[1]) + (a[2] + a[3]);
          }
          __builtin_amdgcn_s_setprio(0);
        }
      }
    }
  };
  auto eper = [&](const bool G, int p, int pp) {
    uint4 xq0[8], xq1[8];
    esub(G, p, pp, 0, xq0, xq1);
    WAVE_SYNC();
    esub(G, p, pp, 1, xq0, xq1);
    BLOCK_SYNC();
  };

  for (int p = 0; p < 3; ++p) eper(true, p, p & 1);
  for (int p = 3; p <= 251; p += 2) { eper(false, p, 1); eper(false, p + 1, 0); }
  for (int p = 253; p <= 257; ++p) eper(true, p, p & 1);

  // ---------------- phase switch: decoder weights ----------------
  c = 0.f;
  if (tid < 32) { hb1d[0][tid] = (half_t)0.f; hb1d[1][tid] = (half_t)0.f;
                  hb1d[2][tid] = (half_t)0.f; hb1d[3][tid] = (half_t)0.f; }
  if (tid < 48) { hb2d[0][tid] = (half_t)0.f; hb2d[1][tid] = (half_t)0.f;
                  hb2d[2][tid] = (half_t)0.f; hb2d[3][tid] = (half_t)0.f; }
  if (tid < 64) { hb3r[0][tid] = (half_t)0.f; hb3r[1][tid] = (half_t)0.f; }

  if (role == 0) {  // d1 pair (latent folded from LDS) + xg_d2 rows
    const int u = l & 31, g0 = (l < 32) ? 0 : 2;
#pragma unroll
    for (int j = 0; j < 2; ++j) {
      const int r = (g0 + j) * 32 + u;
      load_row_h2(U3 + (size_t)r * 32, 32, w + j * 16);
      float s0 = b3i[r] + b3h[r];
      const float* wr = W3 + (size_t)r * 16;
#pragma unroll
      for (int d = 0; d < 16; ++d) s0 = fmaf(wr[d], latb[d], s0);
      bias[j] = s0;
      gconst(g0 + j, sA[j], aA[j], bB[j]);
    }
#pragma unroll
    for (int jj = 0; jj < 3; ++jj) {
      const int r = 64 * jj + l;
      load_row_h2(W4 + (size_t)r * 32, 32, w + 32 + jj * 16);
      bx[jj] = b4i[r] + b4h[r];
    }
  } else if (role == 1) {  // d2-rec unit-per-lane (H=48)
#pragma unroll
    for (int j = 0; j < 4; ++j)
      load_row_h2(U4 + (size_t)(j * 48 + uu) * 48, 48, w + j * 24);
  } else if (role == 2) {  // d3-rec unit-per-lane (H=64): U5 rows j*64+l
#pragma unroll
    for (int j = 0; j < 4; ++j)
      load_row_h2(U5 + (size_t)(j * 64 + l) * 64, 64, w + j * 32);
  } else {  // d3-xg producer: W5 rows 64j+l (bias folded)
#pragma unroll
    for (int j = 0; j < 4; ++j) {
      const int r = 64 * j + l;
      load_row_h2(W5 + (size_t)r * 48, 48, w + j * 24);
      bx[j] = b5i[r] + b5h[r];
    }
  }
  BLOCK_SYNC();

  // ---------------- decoder: one barrier per 2 steps ----------------
  auto dsub = [&](const bool G, int p, int pp, int sub) {
    if (role == 0) {
      const int t_ = 2 * p + sub;
      uint4 hq[4];
      fetch_q<4>(&hb1d[(2 * pp + sub + 3) & 3][0], hq);
      if (!G || t_ < T) {
        float gv[2];
#pragma unroll
        for (int j = 0; j < 2; ++j) {
          float a[4] = {bias[j], 0.f, 0.f, 0.f};
          dot4<4>(w + j * 16, hq, a);
          gv[j] = act_rt((a[0] + a[1]) + (a[2] + a[3]), sA[j], aA[j], bB[j]);
        }
        float h = pair_combine(gv[0], gv[1], l, c);
        if (l < 32) hb1d[(2 * pp + sub) & 3][l & 31] = (half_t)h;
      }
      if (!G || ((t_ >= 1) && (t_ <= T))) {
#pragma unroll
        for (int jj = 0; jj < 3; ++jj) {
          float a[4] = {bx[jj], 0.f, 0.f, 0.f};
          dot4<4>(w + 32 + jj * 16, hq, a);
          xg2[pp][sub][64 * jj + l] = (a[0] + a[1]) + (a[2] + a[3]);
        }
      }
    } else if (role == 1) {
      const int t_ = 2 * p + sub - 3;
      if (!G || (unsigned)t_ < (unsigned)T) {
        float xgv[4];
#pragma unroll
        for (int j = 0; j < 4; ++j) xgv[j] = xg2[pp ^ 1][sub][j * 48 + uu];
        uint4 hq[6];
        fetch_q<6>(&hb2d[(2 * pp + sub) & 3][0], hq);
        __builtin_amdgcn_s_setprio(1);
        float gv[4];
#pragma unroll
        for (int j = 0; j < 4; ++j) {
          float a[4] = {xgv[j], 0.f, 0.f, 0.f};
          dot4<6>(w + j * 24, hq, a);
          float pre = (a[0] + a[1]) + (a[2] + a[3]);
          gv[j] = (j == 2) ? act_tanh(pre) : act_sig(pre);
        }
        __builtin_amdgcn_s_setprio(0);
        float h = comb4(gv[0], gv[1], gv[2], gv[3], c);
        if (l < 48) hb2d[(2 * pp + sub + 1) & 3][l] = (half_t)h;
      }
    } else if (role == 2) {  // d3-rec, skew 7, unit l
      const int t_ = 2 * p + sub - 7;
      if (!G || (unsigned)t_ < (unsigned)T) {
        float xgv[4];
#pragma unroll
        for (int j = 0; j < 4; ++j) xgv[j] = xg3[pp ^ 1][sub][64 * j + l];
        uint4 hq[8];
        fetch_q<8>(&hb3r[sub ^ 1][0], hq);
        __builtin_amdgcn_s_setprio(1);
        float gv[4];
#pragma unroll
        for (int j = 0; j < 4; ++j) {
          float a[4] = {xgv[j], 0.f, 0.f, 0.f};
          dot4<8>(w + j * 32, hq, a);
          float pre = (a[0] + a[1]) + (a[2] + a[3]);
          gv[j] = (j == 2) ? act_tanh(pre) : act_sig(pre);
        }
        __builtin_amdgcn_s_setprio(0);
        float h = comb4(gv[0], gv[1], gv[2], gv[3], c);
        hb3r[sub][l] = (half_t)h;
        out[((size_t)b * T + t_) * 64 + l] = h;
      }
    } else {  // d3-xg: W5 @ h2d[tau], tau = s-5, consumed next period
      const int tau = 2 * p + sub - 5;
      if (!G || (unsigned)tau < (unsigned)T) {
        uint4 xv[6];
        fetch_q<6>(&hb2d[(2 * pp + sub + 3) & 3][0], xv);
        __builtin_amdgcn_s_setprio(1);
#pragma unroll
        for (int j = 0; j < 4; ++j) {
          float a[4] = {bx[j], 0.f, 0.f, 0.f};
          dot4<6>(w + j * 24, xv, a);
          xg3[pp][sub][64 * j + l] = (a[0] + a[1]) + (a[2] + a[3]);
        }
        __builtin_amdgcn_s_setprio(0);
      }
    }
  };
  auto dper = [&](const bool G, int p, int pp) {
    dsub(G, p, pp, 0);
    WAVE_SYNC();
    dsub(G, p, pp, 1);
    BLOCK_SYNC();
  };

  for (int p = 0; p < 4; ++p) dper(true, p, p & 1);
  for (int p = 4; p <= 254; p += 2) { dper(false, p, 0); dper(false, p + 1, 1); }
  for (int p = 256; p <= 259; ++p) dper(true, p, p & 1);
}

extern "C" void kernel_launch(void* const* d_in, const int* in_sizes, int n_in,
                              void* d_out, int out_size, void* d_ws, size_t ws_size,
                              hipStream_t stream) {
  (void)in_sizes; (void)n_in; (void)out_size; (void)d_ws; (void)ws_size;
  const float* x = (const float*)d_in[0];
  const float *W[6], *U[6], *Bi[6], *Bh[6];
  for (int lyr = 0; lyr < 6; ++lyr) {
    W[lyr]  = (const float*)d_in[1 + 4 * lyr + 0];
    U[lyr]  = (const float*)d_in[1 + 4 * lyr + 1];
    Bi[lyr] = (const float*)d_in[1 + 4 * lyr + 2];
    Bh[lyr] = (const float*)d_in[1 + 4 * lyr + 3];
  }
  float* out = (float*)d_out;
  const int T = 512;

  ae_ker<<<dim3(512), dim3(256), 0, stream>>>(
      W[0], U[0], Bi[0], Bh[0], W[1], U[1], Bi[1], Bh[1], W[2], U[2], Bi[2], Bh[2],
      W[3], U[3], Bi[3], Bh[3], W[4], U[4], Bi[4], Bh[4], W[5], U[5], Bi[5], Bh[5],
      x, out, T);
}

// Round 11
// 722.383 us; speedup vs baseline: 11.3525x; 11.3525x over previous
//
#include <hip/hip_runtime.h>
#include <hip/hip_bf16.h>
#include <cstdint>
#include <cstddef>

typedef _Float16 half_t;
typedef decltype(__builtin_amdgcn_cvt_pkrtz(0.f, 0.f)) h2;  // v2f16

__device__ __forceinline__ h2 pk2(float a, float b) { return __builtin_amdgcn_cvt_pkrtz(a, b); }
__device__ __forceinline__ float fdot2f(h2 a, h2 b, float c) { return __builtin_amdgcn_fdot2(a, b, c, false); }
__device__ __forceinline__ h2 u2h(uint32_t u) { union { uint32_t u; h2 h; } v; v.u = u; return v.h; }

#define WAVE_SYNC() asm volatile("s_waitcnt lgkmcnt(0)" ::: "memory")
// Block barrier WITHOUT vmcnt drain: global loads stay in flight.
#define BLOCK_SYNC()                                   \
  do {                                                 \
    asm volatile("s_waitcnt lgkmcnt(0)" ::: "memory"); \
    __builtin_amdgcn_s_barrier();                      \
    asm volatile("" ::: "memory");                     \
  } while (0)

template <int NQ>
__device__ __forceinline__ void fetch_q(const half_t* hb, uint4* q) {
  const uint4* p = (const uint4*)hb;
#pragma unroll
  for (int i = 0; i < NQ; ++i) q[i] = p[i];
}

// 8 f16-MACs per uint4, FOUR independent accumulator chains.
template <int NQ>
__device__ __forceinline__ void dot4(const h2* w, const uint4* q, float* a) {
#pragma unroll
  for (int i = 0; i < NQ; ++i) {
    a[0] = fdot2f(w[4 * i + 0], u2h(q[i].x), a[0]);
    a[1] = fdot2f(w[4 * i + 1], u2h(q[i].y), a[1]);
    a[2] = fdot2f(w[4 * i + 2], u2h(q[i].z), a[2]);
    a[3] = fdot2f(w[4 * i + 3], u2h(q[i].w), a[3]);
  }
}

__device__ __forceinline__ void load_row_h2(const float* src, int nf, h2* dst) {
  const float2* s2 = (const float2*)src;
  for (int p = 0; p < nf / 2; ++p) { float2 v = s2[p]; dst[p] = pk2(v.x, v.y); }
}

__device__ __forceinline__ void gconst(int gt, float& s, float& a, float& b) {
  const bool isT = (gt == 2);
  s = isT ? -2.88539008f : -1.44269504f;
  a = isT ? 2.f : 1.f;
  b = isT ? -1.f : 0.f;
}

__device__ __forceinline__ float act_sig(float x) {
  float e = exp2f(-1.44269504f * x);
  return __builtin_amdgcn_rcpf(1.f + e);
}
__device__ __forceinline__ float act_tanh(float x) {
  float e = exp2f(-2.88539008f * x);
  return fmaf(2.f, __builtin_amdgcn_rcpf(1.f + e), -1.f);
}
__device__ __forceinline__ float act_rt(float x, float s, float a, float b) {
  float e = exp2f(s * x);
  return fmaf(a, __builtin_amdgcn_rcpf(1.f + e), b);
}

__device__ __forceinline__ float comb4(float gi, float gf, float gg, float go, float& c) {
  c = fmaf(gf, c, gi * gg);
  float e2 = exp2f(-2.88539008f * c);
  return go * fmaf(2.f, __builtin_amdgcn_rcpf(1.f + e2), -1.f);
}

// Pair layers (pow2 H): lane l<32 computed gates (i,f), lane l+32 (g,o) of the
// same unit. One shfl_xor(32) pair completes the set.
__device__ __forceinline__ float pair_combine(float gv0, float gv1, int l, float& c) {
  float sw0 = __shfl_xor(gv0, 32, 64);
  float sw1 = __shfl_xor(gv1, 32, 64);
  const bool lo = (l < 32);
  float gi = lo ? gv0 : sw0, gf = lo ? gv1 : sw1;
  float gg = lo ? sw0 : gv0, go = lo ? sw1 : gv1;
  return comb4(gi, gf, gg, go, c);
}

// ===================== Fused autoencoder (R8 structure: 1 barrier/step) ==========
// 512 blocks x 256 threads, one block per batch chain, enc phase then dec phase.
// Enc: wv0=e1-rec(96d) wv1=e2 pair(80d) wv2=e3(24d) wv3=producer(x+e1-xGEMM)
// Dec: wv0=d1+xg_d2(80d) wv1=d2-rec(96d) wv2,3=d3 pair halves(112d)
// Max per-role weight footprint 112 h2 -> stays in VGPRs (verified R8: VGPR=120,
// no scratch). Do NOT grow any role past this (R10: 128 h2 -> scratch spill, 11x).
__global__ __launch_bounds__(256, 2) void ae_ker(
    const float* __restrict__ W0, const float* __restrict__ U0, const float* __restrict__ b0i, const float* __restrict__ b0h,
    const float* __restrict__ W1, const float* __restrict__ U1, const float* __restrict__ b1i, const float* __restrict__ b1h,
    const float* __restrict__ W2, const float* __restrict__ U2, const float* __restrict__ b2i, const float* __restrict__ b2h,
    const float* __restrict__ W3, const float* __restrict__ U3, const float* __restrict__ b3i, const float* __restrict__ b3h,
    const float* __restrict__ W4, const float* __restrict__ U4, const float* __restrict__ b4i, const float* __restrict__ b4h,
    const float* __restrict__ W5, const float* __restrict__ U5, const float* __restrict__ b5i, const float* __restrict__ b5h,
    const float* __restrict__ x, float* __restrict__ out, int T) {
  __shared__ __align__(16) half_t hb1e[2][48];
  __shared__ __align__(16) half_t hb2e[2][32];
  __shared__ __align__(16) half_t hb3e[2][16];
  __shared__ __align__(16) uint32_t xrow16[2][32];
  __shared__ __align__(16) float xg1[2][192];
  __shared__ __align__(16) float latb[16];
  __shared__ __align__(16) half_t hb1d[2][32];
  __shared__ __align__(16) half_t hb2d[2][48];
  __shared__ __align__(16) half_t hb3d[2][64];
  __shared__ __align__(16) float xg2[2][192];

  const int tid = threadIdx.x, wv = tid >> 6, l = tid & 63, b = blockIdx.x;
  const int uu = (l < 48) ? l : 47;

  if (tid < 48) { hb1e[0][tid] = (half_t)0.f; hb1e[1][tid] = (half_t)0.f; }
  if (tid < 32) { hb2e[0][tid] = (half_t)0.f; hb2e[1][tid] = (half_t)0.f; }
  if (tid < 16) { hb3e[0][tid] = (half_t)0.f; hb3e[1][tid] = (half_t)0.f; }

  h2 w[112];
  float bias[3] = {0.f, 0.f, 0.f};
  float bx[3] = {0.f, 0.f, 0.f};
  float sA[2], aA[2], bB[2];
  float c = 0.f;
  float2 va = {0.f, 0.f}, vb = {0.f, 0.f};
  const float2* xp = nullptr;

  // ---------------- encoder weight load ----------------
  if (wv == 0) {  // e1-rec: unit-per-lane, Whh rows j*48+uu
#pragma unroll
    for (int j = 0; j < 4; ++j)
      load_row_h2(U0 + (size_t)(j * 48 + uu) * 48, 48, w + j * 24);
  } else if (wv == 1) {  // e2 pair
    const int u = l & 31, g0 = (l < 32) ? 0 : 2;
#pragma unroll
    for (int j = 0; j < 2; ++j) {
      const int r = (g0 + j) * 32 + u;
      load_row_h2(W1 + (size_t)r * 48, 48, w + j * 40);
      load_row_h2(U1 + (size_t)r * 32, 32, w + j * 40 + 24);
      bias[j] = b1i[r] + b1h[r];
      gconst(g0 + j, sA[j], aA[j], bB[j]);
    }
  } else if (wv == 2) {  // e3: row r=l
    load_row_h2(W2 + (size_t)l * 32, 32, w);
    load_row_h2(U2 + (size_t)l * 16, 16, w + 16);
    bias[0] = b2i[l] + b2h[l];
    gconst(l >> 4, sA[0], aA[0], bB[0]);
  } else {  // producer: Wih_e1 rows 64j+l
#pragma unroll
    for (int j = 0; j < 3; ++j) {
      const int r = 64 * j + l;
      load_row_h2(W0 + (size_t)r * 64, 64, w + j * 32);
      bias[j] = b0i[r] + b0h[r];
    }
    xp = (const float2*)(x + (size_t)b * T * 64) + (l & 31);
    if (l < 32) {
      float2 x0 = xp[0], x1 = xp[32];
      union { h2 h; uint32_t u; } c0, c1;
      c0.h = pk2(x0.x, x0.y);
      c1.h = pk2(x1.x, x1.y);
      xrow16[0][l] = c0.u;
      xrow16[1][l] = c1.u;
      va = xp[64];
      vb = xp[96];
    }
    WAVE_SYNC();
    uint4 xq[8];
    const uint4* xr = (const uint4*)&xrow16[0][0];
#pragma unroll
    for (int i = 0; i < 8; ++i) xq[i] = xr[i];
#pragma unroll
    for (int j = 0; j < 3; ++j) {
      float a[4] = {bias[j], 0.f, 0.f, 0.f};
      dot4<8>(w + j * 32, xq, a);
      xg1[0][64 * j + l] = (a[0] + a[1]) + (a[2] + a[3]);
    }
  }
  BLOCK_SYNC();

  // ---------------- encoder loop ----------------
  auto estep = [&](const bool G, int s, int P) {
    const int Q = P ^ 1;
    if (wv == 0) {
      if (!G || s < T) {
        float xgv[4];
#pragma unroll
        for (int j = 0; j < 4; ++j) xgv[j] = xg1[P][j * 48 + uu];
        uint4 hq[6];
        fetch_q<6>(&hb1e[Q][0], hq);
        __builtin_amdgcn_s_setprio(1);
        float gv[4];
#pragma unroll
        for (int j = 0; j < 4; ++j) {
          float a[4] = {xgv[j], 0.f, 0.f, 0.f};
          dot4<6>(w + j * 24, hq, a);
          float pre = (a[0] + a[1]) + (a[2] + a[3]);
          gv[j] = (j == 2) ? act_tanh(pre) : act_sig(pre);
        }
        __builtin_amdgcn_s_setprio(0);
        float h = comb4(gv[0], gv[1], gv[2], gv[3], c);
        if (l < 48) hb1e[P][l] = (half_t)h;
      }
    } else if (wv == 1) {
      if (!G || (s >= 1 && s <= T)) {
        uint4 xv[6], hq[4];
        fetch_q<6>(&hb1e[Q][0], xv);
        fetch_q<4>(&hb2e[Q][0], hq);
        float gv[2];
#pragma unroll
        for (int j = 0; j < 2; ++j) {
          float a[4] = {bias[j], 0.f, 0.f, 0.f};
          dot4<6>(w + j * 40, xv, a);
          dot4<4>(w + j * 40 + 24, hq, a);
          gv[j] = act_rt((a[0] + a[1]) + (a[2] + a[3]), sA[j], aA[j], bB[j]);
        }
        float h = pair_combine(gv[0], gv[1], l, c);
        if (l < 32) hb2e[P][l & 31] = (half_t)h;
      }
    } else if (wv == 2) {
      if (!G || s >= 2) {
        uint4 xv[4], hq[2];
        fetch_q<4>(&hb2e[Q][0], xv);
        fetch_q<2>(&hb3e[Q][0], hq);
        float a[4] = {bias[0], 0.f, 0.f, 0.f};
        dot4<4>(w, xv, a);
        dot4<2>(w + 16, hq, a);
        float gvv = act_rt((a[0] + a[1]) + (a[2] + a[3]), sA[0], aA[0], bB[0]);
        float s1 = __shfl_xor(gvv, 16, 64);
        float r0 = __shfl_xor(gvv, 32, 64);
        float r1 = __shfl_xor(s1, 32, 64);
        float h = comb4(gvv, s1, r0, r1, c);
        if (l < 16) {
          hb3e[P][l] = (half_t)h;
          if (G && s - 2 == T - 1) latb[l] = h;
        }
      }
    } else {
      if ((!G || s + 2 < T) && l < 32) {
        union { h2 h; uint32_t u; } cc2;
        float2 v = P ? vb : va;
        cc2.h = pk2(v.x, v.y);
        xrow16[P][l] = cc2.u;
        if (!G || s + 4 < T) {
          float2 nv = xp[(size_t)(s + 4) * 32];
          if (P) vb = nv; else va = nv;
        }
      }
      if (!G || s + 1 < T) {
        WAVE_SYNC();
        uint4 xq[8];
        const uint4* xr = (const uint4*)&xrow16[Q][0];
#pragma unroll
        for (int i = 0; i < 8; ++i) xq[i] = xr[i];
        __builtin_amdgcn_s_setprio(1);
#pragma unroll
        for (int j = 0; j < 3; ++j) {
          float a[4] = {bias[j], 0.f, 0.f, 0.f};
          dot4<8>(w + j * 32, xq, a);
          xg1[Q][64 * j + l] = (a[0] + a[1]) + (a[2] + a[3]);
        }
        __builtin_amdgcn_s_setprio(0);
      }
    }
    BLOCK_SYNC();
  };

  {
    const int NS = T + 2;  // 514
    for (int s = 0; s < 4; ++s) estep(true, s, s & 1);
    for (int s = 4; s < 508; s += 2) { estep(false, s, 0); estep(false, s + 1, 1); }
    for (int s = 508; s < NS; ++s) estep(true, s, s & 1);
  }

  // ---------------- phase switch: decoder weights ----------------
  c = 0.f;
  if (tid < 32) { hb1d[0][tid] = (half_t)0.f; hb1d[1][tid] = (half_t)0.f; }
  if (tid < 48) { hb2d[0][tid] = (half_t)0.f; hb2d[1][tid] = (half_t)0.f; }
  if (tid < 64) { hb3d[0][tid] = (half_t)0.f; hb3d[1][tid] = (half_t)0.f; }
  const int u2 = (l & 31) + ((wv == 3) ? 32 : 0);  // d3 unit

  if (wv == 0) {  // d1 pair (latent folded from LDS) + xg_d2 rows
    const int u = l & 31, g0 = (l < 32) ? 0 : 2;
#pragma unroll
    for (int j = 0; j < 2; ++j) {
      const int r = (g0 + j) * 32 + u;
      load_row_h2(U3 + (size_t)r * 32, 32, w + j * 16);
      float s0 = b3i[r] + b3h[r];
      const float* wr = W3 + (size_t)r * 16;
#pragma unroll
      for (int d = 0; d < 16; ++d) s0 = fmaf(wr[d], latb[d], s0);
      bias[j] = s0;
      gconst(g0 + j, sA[j], aA[j], bB[j]);
    }
#pragma unroll
    for (int jj = 0; jj < 3; ++jj) {
      const int r = 64 * jj + l;
      load_row_h2(W4 + (size_t)r * 32, 32, w + 32 + jj * 16);
      bx[jj] = b4i[r] + b4h[r];
    }
  } else if (wv == 1) {  // d2-rec unit-per-lane
#pragma unroll
    for (int j = 0; j < 4; ++j)
      load_row_h2(U4 + (size_t)(j * 48 + uu) * 48, 48, w + j * 24);
  } else {  // d3 pair halves
    const int g0 = (l < 32) ? 0 : 2;
#pragma unroll
    for (int j = 0; j < 2; ++j) {
      const int r = (g0 + j) * 64 + u2;
      load_row_h2(W5 + (size_t)r * 48, 48, w + j * 56);
      load_row_h2(U5 + (size_t)r * 64, 64, w + j * 56 + 24);
      bias[j] = b5i[r] + b5h[r];
      gconst(g0 + j, sA[j], aA[j], bB[j]);
    }
  }
  BLOCK_SYNC();

  // ---------------- decoder loop ----------------
  auto dstep = [&](const bool G, int s, int P) {
    const int Q = P ^ 1;
    if (wv == 0) {
      if (!G || s <= T) {
        uint4 hq[4];
        fetch_q<4>(&hb1d[Q][0], hq);
        if (!G || s < T) {
          float gv[2];
#pragma unroll
          for (int j = 0; j < 2; ++j) {
            float a[4] = {bias[j], 0.f, 0.f, 0.f};
            dot4<4>(w + j * 16, hq, a);
            gv[j] = act_rt((a[0] + a[1]) + (a[2] + a[3]), sA[j], aA[j], bB[j]);
          }
          float h = pair_combine(gv[0], gv[1], l, c);
          if (l < 32) hb1d[P][l & 31] = (half_t)h;
        }
        if (!G || s >= 1) {
#pragma unroll
          for (int jj = 0; jj < 3; ++jj) {
            float a[4] = {bx[jj], 0.f, 0.f, 0.f};
            dot4<4>(w + 32 + jj * 16, hq, a);
            xg2[P][64 * jj + l] = (a[0] + a[1]) + (a[2] + a[3]);
          }
        }
      }
    } else if (wv == 1) {
      if (!G || (s >= 2 && s < T + 2)) {
        float xgv[4];
#pragma unroll
        for (int j = 0; j < 4; ++j) xgv[j] = xg2[Q][j * 48 + uu];
        uint4 hq[6];
        fetch_q<6>(&hb2d[Q][0], hq);
        __builtin_amdgcn_s_setprio(1);
        float gv[4];
#pragma unroll
        for (int j = 0; j < 4; ++j) {
          float a[4] = {xgv[j], 0.f, 0.f, 0.f};
          dot4<6>(w + j * 24, hq, a);
          float pre = (a[0] + a[1]) + (a[2] + a[3]);
          gv[j] = (j == 2) ? act_tanh(pre) : act_sig(pre);
        }
        __builtin_amdgcn_s_setprio(0);
        float h = comb4(gv[0], gv[1], gv[2], gv[3], c);
        if (l < 48) hb2d[P][l] = (half_t)h;
      }
    } else {
      if (!G || (s >= 3 && s < T + 3)) {
        uint4 xv[6], hq[8];
        fetch_q<6>(&hb2d[Q][0], xv);
        fetch_q<8>(&hb3d[Q][0], hq);
        __builtin_amdgcn_s_setprio(1);
        float gv[2];
#pragma unroll
        for (int j = 0; j < 2; ++j) {
          float a[4] = {bias[j], 0.f, 0.f, 0.f};
          dot4<6>(w + j * 56, xv, a);
          dot4<8>(w + j * 56 + 24, hq, a);
          gv[j] = act_rt((a[0] + a[1]) + (a[2] + a[3]), sA[j], aA[j], bB[j]);
        }
        __builtin_amdgcn_s_setprio(0);
        float h = pair_combine(gv[0], gv[1], l, c);
        if (l < 32) {
          hb3d[P][u2] = (half_t)h;
          out[((size_t)b * T + (s - 3)) * 64 + u2] = h;
        }
      }
    }
    BLOCK_SYNC();
  };

  {
    const int NS = T + 4;  // 516
    for (int s = 0; s < 4; ++s) dstep(true, s, s & 1);
    for (int s = 4; s < 508; s += 2) { dstep(false, s, 0); dstep(false, s + 1, 1); }
    for (int s = 508; s < NS; ++s) dstep(true, s, s & 1);
  }
}

extern "C" void kernel_launch(void* const* d_in, const int* in_sizes, int n_in,
                              void* d_out, int out_size, void* d_ws, size_t ws_size,
                              hipStream_t stream) {
  (void)in_sizes; (void)n_in; (void)out_size; (void)d_ws; (void)ws_size;
  const float* x = (const float*)d_in[0];
  const float *W[6], *U[6], *Bi[6], *Bh[6];
  for (int lyr = 0; lyr < 6; ++lyr) {
    W[lyr]  = (const float*)d_in[1 + 4 * lyr + 0];
    U[lyr]  = (const float*)d_in[1 + 4 * lyr + 1];
    Bi[lyr] = (const float*)d_in[1 + 4 * lyr + 2];
    Bh[lyr] = (const float*)d_in[1 + 4 * lyr + 3];
  }
  float* out = (float*)d_out;
  const int T = 512;

  ae_ker<<<dim3(512), dim3(256), 0, stream>>>(
      W[0], U[0], Bi[0], Bh[0], W[1], U[1], Bi[1], Bh[1], W[2], U[2], Bi[2], Bh[2],
      W[3], U[3], Bi[3], Bh[3], W[4], U[4], Bi[4], Bh[4], W[5], U[5], Bi[5], Bh[5],
      x, out, T);
}